// Round 4
// baseline (371.235 us; speedup 1.0000x reference)
//
#include <hip/hip_runtime.h>

#define Hdim 512
#define Wdim 512
#define Cdim 64
#define HWSZ (Hdim * Wdim)
#define TH 8
#define TW 32
#define IH 12
#define IW 36
#define NL (IH * IW)            // 432 tile-input pixels
#define NCHUNK (NL * 8)         // 3456 16B chunks
#define SX_BYTES (NL * 128)     // 55296
#define WB_OFF SX_BYTES         // 2 x 8192 weight double-buffer
#define SMASK_OFF (SX_BYTES + 16384)    // 71680
#define LDS_TOTAL (SMASK_OFF + NL * 4)  // 73408

typedef __attribute__((ext_vector_type(8))) short short8;
typedef __attribute__((ext_vector_type(4))) float f32x4;
typedef __attribute__((ext_vector_type(4))) int   i32x4;

__device__ __forceinline__ int reflect_idx(int i) {
    i = abs(i);
    if (i >= Hdim) i = 2 * Hdim - 2 - i;
    return i;
}
__device__ __forceinline__ unsigned bf16_1(float f) {
    unsigned u = __float_as_uint(f);
    return (u + 0x7FFF + ((u >> 16) & 1)) >> 16;   // RNE
}
__device__ __forceinline__ unsigned bf16pk(float lo, float hi) {
    return bf16_1(lo) | (bf16_1(hi) << 16);
}
__device__ __forceinline__ float gelu_fast(float v) {
    float u = v * fmaf(v * v, 0.0713548162726f, 1.59576912161f);
    return v / (1.0f + __expf(-u));
}
__device__ __forceinline__ void gl16(const void* g, void* l) {
    __builtin_amdgcn_global_load_lds(
        (const __attribute__((address_space(1))) unsigned int*)g,
        (__attribute__((address_space(3))) unsigned int*)l, 16, 0, 0);
}

// ---------------- P: x fp32 NCHW -> xbf bf16 NHWC ----------------
__global__ __launch_bounds__(256) void tposek(
    const float* __restrict__ x, unsigned short* __restrict__ xbf)
{
    const int lane = threadIdx.x & 63, wv = threadIdx.x >> 6;
    const int pix = blockIdx.x * 256 + wv * 64 + lane;
    #pragma unroll
    for (int q = 0; q < 8; ++q) {
        unsigned pk[4];
        #pragma unroll
        for (int k = 0; k < 4; ++k) {
            float f0 = x[(q * 8 + 2 * k    ) * HWSZ + pix];
            float f1 = x[(q * 8 + 2 * k + 1) * HWSZ + pix];
            pk[k] = bf16pk(f0, f1);
        }
        *(i32x4*)&xbf[(size_t)pix * 64 + q * 8] = *(const i32x4*)pk;
    }
}

// ---------------- mconv: implicit-GEMM 3x3 dil-2 conv via MFMA ----------------
// MODE 0: out_t = md ? gelu(conv)+.. : x  (bf16 NHWC, all pixels), md = 5x5 dilate(mask)
// MODE 1: out_f[sd] = gelu(conv) + xres   (fp32 NCHW, masked)
template <int MODE>
__global__ __launch_bounds__(256, 2) void mconv(
    const unsigned short* __restrict__ xin_t,   // bf16 NHWC input
    const float* __restrict__ mask,
    const float* __restrict__ wgt,    // (64,64,3,3) fp32 OIHW
    const float* __restrict__ bias,
    const float* __restrict__ xres,   // x fp32 NCHW
    unsigned short* __restrict__ out_t,
    float* __restrict__ out_f)
{
    __shared__ __align__(16) unsigned char lds[LDS_TOTAL];
    float* smask = (float*)(lds + SMASK_OFF);

    const int tid  = threadIdx.x;
    const int lane = tid & 63;
    const int wv   = tid >> 6;
    const int bx   = blockIdx.x & 15;
    const int by   = blockIdx.x >> 4;
    const int ox0  = bx * TW, oy0 = by * TH;

    f32x4 acc[4][4];
    #pragma unroll
    for (int fr = 0; fr < 4; ++fr) {
        f32x4 b;
        #pragma unroll
        for (int r = 0; r < 4; ++r) b[r] = bias[fr * 16 + (lane >> 4) * 4 + r];
        #pragma unroll
        for (int fc = 0; fc < 4; ++fc) acc[fr][fc] = b;
    }

    // ---- prologue: stage full input tile via global_load_lds (swizzled source) ----
    #pragma unroll 1
    for (int it = 0; it < 14; ++it) {
        int qb = it * 256 + wv * 64;
        if (qb < NCHUNK) {
            int q = qb + lane;
            int L = q >> 3, j = q & 7;
            int tr = L / IW, tc = L - tr * IW;
            int r = reflect_idx(oy0 - 2 + tr);
            int c = reflect_idx(ox0 - 2 + tc);
            int jj = j ^ (L & 7);   // inverse swizzle on source; LDS stays linear
            gl16(xin_t + ((size_t)(r * Wdim + c) << 6) + (jj << 3),
                 (void*)(lds + qb * 16 + lane * 16));
        }
    }
    // stage tap-0 weights into wbuf0
    {
        unsigned char* wb = lds + WB_OFF;
        #pragma unroll
        for (int it = 0; it < 2; ++it) {
            int q = it * 256 + tid;
            int h = q >> 8, f = (q >> 6) & 3, l = q & 63;
            int co = f * 16 + (l & 15);
            int ci = h * 32 + ((l >> 4) << 3);
            const float* wp = wgt + (co * 64 + ci) * 9 + 0;
            i32x4 v;
            v.x = bf16pk(wp[0],  wp[9]);
            v.y = bf16pk(wp[18], wp[27]);
            v.z = bf16pk(wp[36], wp[45]);
            v.w = bf16pk(wp[54], wp[63]);
            *(i32x4*)&wb[q * 16] = v;
        }
    }
    if (MODE == 0) {
        for (int i = tid; i < NL; i += 256) {
            int r = oy0 - 2 + i / IW, c = ox0 - 2 + (i - (i / IW) * IW);
            float m = 0.0f;
            if (r >= 0 && r < Hdim && c >= 0 && c < Wdim) m = mask[r * Wdim + c];
            smask[i] = m;
        }
    }
    __syncthreads();   // drains vmcnt (gload_lds) + lgkm (ds_write)

    // ---- main loop: one tap per barrier, weights double-buffered ----
    #pragma unroll 1
    for (int t = 0; t < 9; ++t) {
        if (t < 8) {   // stage next tap's weights into the other buffer
            const int tn = t + 1;
            unsigned char* wb = lds + WB_OFF + (tn & 1) * 8192;
            #pragma unroll
            for (int it = 0; it < 2; ++it) {
                int q = it * 256 + tid;
                int h = q >> 8, f = (q >> 6) & 3, l = q & 63;
                int co = f * 16 + (l & 15);
                int ci = h * 32 + ((l >> 4) << 3);
                const float* wp = wgt + (co * 64 + ci) * 9 + tn;
                i32x4 v;
                v.x = bf16pk(wp[0],  wp[9]);
                v.y = bf16pk(wp[18], wp[27]);
                v.z = bf16pk(wp[36], wp[45]);
                v.w = bf16pk(wp[54], wp[63]);
                *(i32x4*)&wb[q * 16] = v;
            }
        }
        {
            const unsigned char* wb = lds + WB_OFF + (t & 1) * 8192;
            const int dy = (t / 3) * 2, dx = (t % 3) * 2;
            #pragma unroll
            for (int h = 0; h < 2; ++h) {
                short8 af[4], bfr[4];
                #pragma unroll
                for (int fr = 0; fr < 4; ++fr)
                    af[fr] = *(const short8*)&wb[h * 4096 + fr * 1024 + lane * 16];
                #pragma unroll
                for (int fc = 0; fc < 4; ++fc) {
                    int prr = 2 * wv + (fc >> 1) + dy;
                    int pcc = (fc & 1) * 16 + (lane & 15) + dx;
                    int L = prr * IW + pcc;
                    int cpos = (h * 4 + (lane >> 4)) ^ (L & 7);
                    bfr[fc] = *(const short8*)&lds[L * 128 + cpos * 16];
                }
                #pragma unroll
                for (int fr = 0; fr < 4; ++fr)
                    #pragma unroll
                    for (int fc = 0; fc < 4; ++fc)
                        acc[fr][fc] = __builtin_amdgcn_mfma_f32_16x16x32_bf16(
                            af[fr], bfr[fc], acc[fr][fc], 0, 0, 0);
            }
        }
        __syncthreads();
    }

    // ---- epilogue ----
    if (MODE == 0) {
        float mdv;
        {
            int pr = 2 * wv + (lane >> 5), pc = lane & 31;
            float m = 0.0f;
            #pragma unroll
            for (int dy = 0; dy < 5; ++dy)
                #pragma unroll
                for (int dx = 0; dx < 5; ++dx)
                    m = fmaxf(m, smask[(pr + dy) * IW + pc + dx]);
            mdv = m;
        }
        __syncthreads();
        unsigned char* bounce = lds + wv * 8192;
        #pragma unroll
        for (int fc = 0; fc < 4; ++fc) {
            float msel = __shfl(mdv, fc * 16 + (lane & 15), 64);
            bool md = msel > 0.5f;
            int p = fc * 16 + (lane & 15);
            int gpix = (oy0 + 2 * wv + (p >> 5)) * Wdim + ox0 + (p & 31);
            int g = lane >> 4;
            #pragma unroll
            for (int fr = 0; fr < 4; ++fr) {
                int co0 = fr * 16 + g * 4;
                unsigned pk0, pk1;
                if (md) {
                    pk0 = bf16pk(gelu_fast(acc[fr][fc][0]), gelu_fast(acc[fr][fc][1]));
                    pk1 = bf16pk(gelu_fast(acc[fr][fc][2]), gelu_fast(acc[fr][fc][3]));
                } else {
                    pk0 = bf16pk(xres[(co0 + 0) * HWSZ + gpix], xres[(co0 + 1) * HWSZ + gpix]);
                    pk1 = bf16pk(xres[(co0 + 2) * HWSZ + gpix], xres[(co0 + 3) * HWSZ + gpix]);
                }
                int cj = fr * 2 + (g >> 1);
                int bo = p * 128 + ((cj ^ (p & 7)) * 16) + (g & 1) * 8;
                *(unsigned*)&bounce[bo]     = pk0;
                *(unsigned*)&bounce[bo + 4] = pk1;
            }
        }
        __syncthreads();
        #pragma unroll
        for (int q = 0; q < 8; ++q) {
            int m   = (q & 3) * 64 + lane;
            int row = 2 * wv + (q >> 2);
            int pp  = (q >> 2) * 32 + (m >> 3);
            int j   = m & 7;
            i32x4 v = *(const i32x4*)&bounce[pp * 128 + ((j ^ (pp & 7)) * 16)];
            *(i32x4*)&out_t[((size_t)((oy0 + row) * Wdim + ox0)) * 64 + m * 8] = v;
        }
    } else {
        #pragma unroll
        for (int fc = 0; fc < 4; ++fc) {
            int p = fc * 16 + (lane & 15);
            int gpix = (oy0 + 2 * wv + (p >> 5)) * Wdim + ox0 + (p & 31);
            bool sd = mask[gpix] > 0.5f;
            if (sd) {
                #pragma unroll
                for (int fr = 0; fr < 4; ++fr) {
                    int co0 = fr * 16 + (lane >> 4) * 4;
                    #pragma unroll
                    for (int r = 0; r < 4; ++r) {
                        float v = gelu_fast(acc[fr][fc][r]) + xres[(co0 + r) * HWSZ + gpix];
                        out_f[(co0 + r) * HWSZ + gpix] = v;
                    }
                }
            }
        }
    }
}

// ---------------- depthwise conv on xbf (NHWC), masked !sd store ----------------
__global__ __launch_bounds__(256) void dwk(
    const unsigned short* __restrict__ xbf,
    const float* __restrict__ mask,
    const float* __restrict__ w3, const float* __restrict__ b3,
    float* __restrict__ out)
{
    __shared__ __align__(16) unsigned char sb[32 * 256];
    const int tid = threadIdx.x;
    const int pl = tid >> 3, j = tid & 7;
    const int pix0 = blockIdx.x * 32;
    const int gpix = pix0 + pl;
    const int r = gpix >> 9, c = gpix & 511;
    const int ci0 = j * 8;

    if (mask[gpix] <= 0.5f) {
        float s[8], resid[8];
        #pragma unroll
        for (int k = 0; k < 8; ++k) s[k] = b3[ci0 + k];
        #pragma unroll
        for (int a = 0; a < 3; ++a) {
            int rr = reflect_idx(r - 2 + 2 * a);
            #pragma unroll
            for (int b = 0; b < 3; ++b) {
                int cc = reflect_idx(c - 2 + 2 * b);
                i32x4 v = *(const i32x4*)&xbf[(size_t)(rr * Wdim + cc) * 64 + ci0];
                const unsigned* u = (const unsigned*)&v;
                #pragma unroll
                for (int k = 0; k < 4; ++k) {
                    float f0 = __uint_as_float(u[k] << 16);
                    float f1 = __uint_as_float(u[k] & 0xFFFF0000u);
                    s[2 * k]     = fmaf(f0, w3[(ci0 + 2 * k) * 9 + a * 3 + b], s[2 * k]);
                    s[2 * k + 1] = fmaf(f1, w3[(ci0 + 2 * k + 1) * 9 + a * 3 + b], s[2 * k + 1]);
                    if (a == 1 && b == 1) { resid[2 * k] = f0; resid[2 * k + 1] = f1; }
                }
            }
        }
        #pragma unroll
        for (int half = 0; half < 2; ++half) {
            f32x4 o;
            #pragma unroll
            for (int k = 0; k < 4; ++k) o[k] = gelu_fast(s[half * 4 + k]) + resid[half * 4 + k];
            int q0 = j * 2 + half;
            *(f32x4*)&sb[pl * 256 + ((q0 ^ (pl & 15)) * 16)] = o;
        }
    }
    __syncthreads();
    #pragma unroll
    for (int it = 0; it < 8; ++it) {
        int m = it * 256 + tid;
        int co = m >> 5, p = m & 31;
        if (mask[pix0 + p] <= 0.5f) {
            int qq = co >> 2;
            float v = *(const float*)&sb[p * 256 + ((qq ^ (p & 15)) * 16) + (co & 3) * 4];
            out[co * HWSZ + pix0 + p] = v;
        }
    }
}

extern "C" void kernel_launch(void* const* d_in, const int* in_sizes, int n_in,
                              void* d_out, int out_size, void* d_ws, size_t ws_size,
                              hipStream_t stream) {
    const float* x    = (const float*)d_in[0];
    const float* mask = (const float*)d_in[1];
    const float* w1   = (const float*)d_in[2];
    const float* b1   = (const float*)d_in[3];
    const float* w2   = (const float*)d_in[4];
    const float* b2   = (const float*)d_in[5];
    const float* w3   = (const float*)d_in[6];
    const float* b3   = (const float*)d_in[7];
    float* out = (float*)d_out;

    unsigned short* xbf  = (unsigned short*)d_ws;                      // 32 MB bf16 NHWC
    unsigned short* xori = (unsigned short*)((char*)d_ws + 33554432);  // 32 MB bf16 NHWC

    const int nblk = (Hdim / TH) * (Wdim / TW);   // 1024

    tposek<<<HWSZ / 256, 256, 0, stream>>>(x, xbf);
    mconv<0><<<nblk, 256, 0, stream>>>(xbf,  mask, w1, b1, x, xori, nullptr);
    mconv<1><<<nblk, 256, 0, stream>>>(xori, mask, w2, b2, x, nullptr, out);
    dwk<<<HWSZ / 32, 256, 0, stream>>>(xbf, mask, w3, b3, out);
}